// Round 2
// baseline (273.336 us; speedup 1.0000x reference)
//
#include <hip/hip_runtime.h>

#define NTOK   2048
#define DIM    512
#define FDIM   2048
#define NEXP   16
#define CAP    768     // max routed tokens buffered per expert (mean ~256)
#define FT     32      // f-rows per K2 block

typedef __bf16 bf16x8 __attribute__((ext_vector_type(8)));
typedef __bf16 bf16x4 __attribute__((ext_vector_type(4)));
typedef float  floatx4 __attribute__((ext_vector_type(4)));

// workspace layout (bytes)
#define WS_COUNTS    0         // 16 ints (memset 0)
#define WS_ZEROPAGE  1024      // 1024B zeros for masked-row loads (memset 0)
#define WS_TOPIDX    4096      // NTOK*2 ints
#define WS_ROUTW     20480     // NTOK*2 floats
#define WS_HMEAN     36864     // NEXP*FDIM floats (plain-stored by K2)
#define WS_YMEAN     167936    // NEXP*DIM floats
#define WS_XG        200704    // NEXP*CAP*DIM bf16 = 12.6 MB
#define WS_ZERO_BYTES 2048     // counts + zero page

// ---------------- K1: gate logits, top-2 softmax, gather x rows (bf16) ------
__global__ __launch_bounds__(256) void k1_route_gather(
    const float* __restrict__ x, const float* __restrict__ gw,
    int* __restrict__ counts, int* __restrict__ top_idx,
    float* __restrict__ routw, __bf16* __restrict__ Xg)
{
    __shared__ float xt[16 * DIM];    // 32 KB: 16 token rows
    __shared__ float lg[16][17];
    __shared__ int   gdst[16][2];
    const int tid = threadIdx.x;
    const int t0  = blockIdx.x * 16;

    {   // stage 16 token rows, coalesced float4
        const float4* src = (const float4*)(x + (size_t)t0 * DIM);
        float4* dst = (float4*)xt;
        #pragma unroll
        for (int i = 0; i < 8; ++i) dst[i * 256 + tid] = src[i * 256 + tid];
    }
    __syncthreads();

    {   // logits: thread = (token tl, expert e)
        const int tl = tid >> 4, e = tid & 15;
        const float4* xr = (const float4*)(xt + tl * DIM);
        const float4* gr = (const float4*)(gw + e * DIM);
        float acc = 0.f;
        #pragma unroll 8
        for (int j = 0; j < DIM / 4; ++j) {
            float4 a = xr[j], b = gr[j];
            acc += a.x * b.x + a.y * b.y + a.z * b.z + a.w * b.w;
        }
        lg[tl][e] = acc;
    }
    __syncthreads();

    if (tid < 16) {   // per-token top-2 + softmax + slot allocation
        const int tl = tid;
        float v0 = -1e30f, v1 = -1e30f; int i0 = 0, i1 = 0;
        #pragma unroll
        for (int e = 0; e < NEXP; ++e) {
            float v = lg[tl][e];
            if (v > v0)      { v1 = v0; i1 = i0; v0 = v; i0 = e; }
            else if (v > v1) { v1 = v;  i1 = e; }
        }
        float e1 = __expf(v1 - v0);          // v0 >= v1
        float w0 = 1.f / (1.f + e1);
        float w1 = 1.f - w0;
        const int t = t0 + tl;
        top_idx[t * 2]     = i0; top_idx[t * 2 + 1] = i1;
        routw[t * 2]       = w0; routw[t * 2 + 1]   = w1;
        int p0 = atomicAdd(counts + i0, 1);
        int p1 = atomicAdd(counts + i1, 1);
        gdst[tl][0] = (p0 < CAP) ? (i0 * CAP + p0) : -1;
        gdst[tl][1] = (p1 < CAP) ? (i1 * CAP + p1) : -1;
    }
    __syncthreads();

    // gather-write 32 rows (16 tokens x 2 experts) as bf16, 8B stores
    #pragma unroll
    for (int it = 0; it < 16; ++it) {
        int s   = it * 256 + tid;          // 0..4095
        int job = s >> 7, el = s & 127;    // job: (token,k), el: float4 index
        int tl  = job >> 1, k = job & 1;
        int dst = gdst[tl][k];
        if (dst >= 0) {
            float4 v = ((const float4*)(xt + tl * DIM))[el];
            bf16x4 o = { (__bf16)v.x, (__bf16)v.y, (__bf16)v.z, (__bf16)v.w };
            *(bf16x4*)(Xg + (size_t)dst * DIM + el * 4) = o;
        }
    }
}

// ---------------- K2: one block per (expert, 32-f-tile) ---------------------
// W1 tile (32f x 512d) LDS-resident bf16 (33 KB -> 4 blocks/CU, grid = one
// full round). B-operand (Xg) loaded DIRECTLY from global into MFMA frags
// (lane (q,l15) reads 16B of token row l15 at d=kga*8) -- no X staging, no
// barriers in the main loop; 16 free-running waves/CU hide the L2 gathers.
// c-outer / 256-token-superchunk-inner so A-frags are register-cached per c.
__global__ __launch_bounds__(256, 4) void k2_expert_ffn(
    const float* __restrict__ w1, const __bf16* __restrict__ Xg,
    const int* __restrict__ counts, const __bf16* __restrict__ zp,
    float* __restrict__ hmean)
{
    __shared__ __align__(16) __bf16 w1s[64 * 33 * 8];   // 33 KB [kg 0..63][f(+pad)][8]
    __shared__ float hred[FT][4];

    const int tid = threadIdx.x;
    const int bid = blockIdx.x;
    const int e   = ((bid & 7) << 1) | (bid >> 9);   // expert -> XCD pinning
    const int f0  = ((bid >> 3) & 63) * FT;
    const int cnt = min(counts[e], CAP);
    const float inv = 1.f / (float)max(cnt, 1);

    const int wv  = tid >> 6;
    const int lane = tid & 63;
    const int q   = lane >> 4;           // mfma k-group
    const int l15 = lane & 15;           // mfma row (f for A, token for B)

    // W1 tile: FT x 512 fp32 -> bf16 LDS, once, coalesced (wave reads 2KB rows)
    #pragma unroll
    for (int it = 0; it < 8; ++it) {
        int s = it * 256 + tid;          // 0..2047
        int kg = s & 63, f = s >> 6;
        const float* src = w1 + ((size_t)(e * FDIM + f0 + f)) * DIM + kg * 8;
        float4 a = ((const float4*)src)[0];
        float4 b = ((const float4*)src)[1];
        bf16x8 v;
        v[0] = (__bf16)a.x; v[1] = (__bf16)a.y; v[2] = (__bf16)a.z; v[3] = (__bf16)a.w;
        v[4] = (__bf16)b.x; v[5] = (__bf16)b.y; v[6] = (__bf16)b.z; v[7] = (__bf16)b.w;
        *(bf16x8*)(w1s + ((size_t)kg * 33 + f) * 8) = v;
    }
    __syncthreads();                     // only barrier in the kernel

    const __bf16* xbase = Xg + (size_t)e * CAP * DIM + q * 8;  // + r*DIM + (c*8+ks*4)*8
    const __bf16* pz    = zp + q * 8;    // masked rows: reads land in [zp, zp+1024)

    float rs[2][4] = {{0.f, 0.f, 0.f, 0.f}, {0.f, 0.f, 0.f, 0.f}};
    const int nsc = (cnt + 255) >> 8;    // super-chunks of 256 tokens

    for (int sc = 0; sc < nsc; ++sc) {
        floatx4 acc[2][2][2];            // [h][fa][tt]
        #pragma unroll
        for (int h = 0; h < 2; ++h)
            #pragma unroll
            for (int a = 0; a < 2; ++a)
                #pragma unroll
                for (int b = 0; b < 2; ++b) acc[h][a][b] = (floatx4)0.f;

        const int b00 = sc * 256 + wv * 32;      // wave's h=0 token base
        const __bf16* p[2][2];                   // [h][tt] row pointers
        #pragma unroll
        for (int h = 0; h < 2; ++h)
            #pragma unroll
            for (int tt = 0; tt < 2; ++tt) {
                int r = b00 + h * 128 + tt * 16 + l15;
                p[h][tt] = (r < cnt) ? (xbase + (size_t)r * DIM) : pz;
            }
        const bool h1 = (b00 + 128) < cnt;       // wave-uniform: is h=1 live?

        #pragma unroll
        for (int c = 0; c < 8; ++c) {
            bf16x8 A[2][2];                      // [ks][fa], register-cached per c
            #pragma unroll
            for (int ks = 0; ks < 2; ++ks)
                #pragma unroll
                for (int fa = 0; fa < 2; ++fa)
                    A[ks][fa] = *(const bf16x8*)(
                        w1s + ((size_t)((c * 8 + ks * 4 + q) * 33) + fa * 16 + l15) * 8);
            #pragma unroll
            for (int ks = 0; ks < 2; ++ks) {
                const int off = (c * 8 + ks * 4) * 8;     // imm-foldable elem offset
                bf16x8 b0 = *(const bf16x8*)(p[0][0] + off);
                bf16x8 b1 = *(const bf16x8*)(p[0][1] + off);
                acc[0][0][0] = __builtin_amdgcn_mfma_f32_16x16x32_bf16(A[ks][0], b0, acc[0][0][0], 0, 0, 0);
                acc[0][0][1] = __builtin_amdgcn_mfma_f32_16x16x32_bf16(A[ks][0], b1, acc[0][0][1], 0, 0, 0);
                acc[0][1][0] = __builtin_amdgcn_mfma_f32_16x16x32_bf16(A[ks][1], b0, acc[0][1][0], 0, 0, 0);
                acc[0][1][1] = __builtin_amdgcn_mfma_f32_16x16x32_bf16(A[ks][1], b1, acc[0][1][1], 0, 0, 0);
                if (h1) {
                    bf16x8 c0 = *(const bf16x8*)(p[1][0] + off);
                    bf16x8 c1 = *(const bf16x8*)(p[1][1] + off);
                    acc[1][0][0] = __builtin_amdgcn_mfma_f32_16x16x32_bf16(A[ks][0], c0, acc[1][0][0], 0, 0, 0);
                    acc[1][0][1] = __builtin_amdgcn_mfma_f32_16x16x32_bf16(A[ks][0], c1, acc[1][0][1], 0, 0, 0);
                    acc[1][1][0] = __builtin_amdgcn_mfma_f32_16x16x32_bf16(A[ks][1], c0, acc[1][1][0], 0, 0, 0);
                    acc[1][1][1] = __builtin_amdgcn_mfma_f32_16x16x32_bf16(A[ks][1], c1, acc[1][1][1], 0, 0, 0);
                }
            }
        }
        // silu + per-lane column-sum (masked rows give silu(0)=0)
        #pragma unroll
        for (int h = 0; h < 2; ++h)
            #pragma unroll
            for (int fa = 0; fa < 2; ++fa)
                #pragma unroll
                for (int r = 0; r < 4; ++r) {
                    float v0 = acc[h][fa][0][r], v1 = acc[h][fa][1][r];
                    rs[fa][r] += v0 / (1.f + __expf(-v0)) + v1 / (1.f + __expf(-v1));
                }
    }

    // reduce over the 16 token-columns held across l15 lanes (once, at end)
    #pragma unroll
    for (int fa = 0; fa < 2; ++fa)
        #pragma unroll
        for (int r = 0; r < 4; ++r) {
            float v = rs[fa][r];
            v += __shfl_xor(v, 1);
            v += __shfl_xor(v, 2);
            v += __shfl_xor(v, 4);
            v += __shfl_xor(v, 8);
            rs[fa][r] = v;
        }
    if (l15 == 0) {
        #pragma unroll
        for (int fa = 0; fa < 2; ++fa)
            #pragma unroll
            for (int r = 0; r < 4; ++r)
                hred[fa * 16 + q * 4 + r][wv] = rs[fa][r];
    }
    __syncthreads();
    if (tid < FT)
        hmean[(size_t)e * FDIM + f0 + tid] =
            (hred[tid][0] + hred[tid][1] + hred[tid][2] + hred[tid][3]) * inv;
}

// ---------------- K3: y_mean[e,d] = h_mean[e,:] . w2[e,d,:]  (fp32) ---------
__global__ __launch_bounds__(256) void k3_ymean(
    const float* __restrict__ w2, const float* __restrict__ hmean,
    const int* __restrict__ counts, float* __restrict__ ymean)
{
    __shared__ float hl[FDIM];           // 8 KB
    const int tid = threadIdx.x;
    const int bid = blockIdx.x;
    const int e   = bid >> 7;
    const int d0  = (bid & 127) * 4;

    {
        const float4* hg = (const float4*)(hmean + (size_t)e * FDIM);
        float4* hl4 = (float4*)hl;
        hl4[tid]       = hg[tid];
        hl4[256 + tid] = hg[256 + tid];
    }
    __syncthreads();

    const int wv = tid >> 6, lane = tid & 63;
    const int d = d0 + wv;
    const float4* wr  = (const float4*)(w2 + ((size_t)e * DIM + d) * FDIM);
    const float4* hl4 = (const float4*)hl;
    float acc = 0.f;
    #pragma unroll
    for (int i = 0; i < 8; ++i) {
        float4 a = wr[i * 64 + lane];
        float4 h = hl4[i * 64 + lane];
        acc += a.x * h.x + a.y * h.y + a.z * h.z + a.w * h.w;
    }
    #pragma unroll
    for (int m = 1; m < 64; m <<= 1) acc += __shfl_xor(acc, m);
    if (lane == 0)
        ymean[e * DIM + d] = (counts[e] > 0) ? acc : 0.f;
}

// ---------------- K4: out[t,:] = w0*y[e0,:] + w1*y[e1,:] --------------------
__global__ __launch_bounds__(256) void k4_combine(
    const int* __restrict__ top_idx, const float* __restrict__ routw,
    const float* __restrict__ ymean, float* __restrict__ out)
{
    const int idx = blockIdx.x * 256 + threadIdx.x;   // float4 index
    const int t = idx >> 7;
    const int c = idx & 127;
    const int i0 = top_idx[t * 2], i1 = top_idx[t * 2 + 1];
    const float w0 = routw[t * 2], w1 = routw[t * 2 + 1];
    float4 a = ((const float4*)(ymean + (size_t)i0 * DIM))[c];
    float4 b = ((const float4*)(ymean + (size_t)i1 * DIM))[c];
    float4 o;
    o.x = w0 * a.x + w1 * b.x;
    o.y = w0 * a.y + w1 * b.y;
    o.z = w0 * a.z + w1 * b.z;
    o.w = w0 * a.w + w1 * b.w;
    ((float4*)out)[idx] = o;
}

extern "C" void kernel_launch(void* const* d_in, const int* in_sizes, int n_in,
                              void* d_out, int out_size, void* d_ws, size_t ws_size,
                              hipStream_t stream)
{
    (void)in_sizes; (void)n_in; (void)out_size; (void)ws_size;
    const float* x  = (const float*)d_in[0];   // [4,512,512]
    const float* gw = (const float*)d_in[1];   // [16,512]
    const float* w1 = (const float*)d_in[2];   // [16,2048,512]
    const float* w2 = (const float*)d_in[3];   // [16,512,2048]
    float* out = (float*)d_out;

    char* ws = (char*)d_ws;
    int*    counts  = (int*)   (ws + WS_COUNTS);
    const __bf16* zp = (const __bf16*)(ws + WS_ZEROPAGE);
    int*    top_idx = (int*)   (ws + WS_TOPIDX);
    float*  routw   = (float*) (ws + WS_ROUTW);
    float*  hmean   = (float*) (ws + WS_HMEAN);
    float*  ymean   = (float*) (ws + WS_YMEAN);
    __bf16* Xg      = (__bf16*)(ws + WS_XG);

    hipMemsetAsync(d_ws, 0, WS_ZERO_BYTES, stream);   // counts + zero page only

    k1_route_gather<<<dim3(NTOK / 16), dim3(256), 0, stream>>>(x, gw, counts, top_idx, routw, Xg);
    k2_expert_ffn  <<<dim3(NEXP * (FDIM / FT)), dim3(256), 0, stream>>>(w1, Xg, counts, zp, hmean);
    k3_ymean       <<<dim3(NEXP * 128), dim3(256), 0, stream>>>(w2, hmean, counts, ymean);
    k4_combine     <<<dim3(NTOK * DIM / 4 / 256), dim3(256), 0, stream>>>(top_idx, routw, ymean, out);
}

// Round 3
// 218.355 us; speedup vs baseline: 1.2518x; 1.2518x over previous
//
#include <hip/hip_runtime.h>

#define NTOK   2048
#define DIM    512
#define FDIM   2048
#define NEXP   16
#define CAP    768     // max routed tokens buffered per expert (mean ~256)
#define BT2    128     // token block per K2 workgroup
#define NTB    (CAP / BT2)   // 6 token-block slots

typedef __bf16 bf16x8 __attribute__((ext_vector_type(8)));
typedef __bf16 bf16x4 __attribute__((ext_vector_type(4)));
typedef float  floatx4 __attribute__((ext_vector_type(4)));

// workspace layout (bytes)
#define WS_COUNTS    0         // 16 ints (memset 0)
#define WS_ZEROPAGE  1024      // >=1KB zeros for pad-lane loads (memset 0)
#define WS_TOPIDX    4096      // NTOK*2 ints
#define WS_ROUTW     20480     // NTOK*2 floats
#define WS_HMEAN     36864     // NEXP*FDIM floats (memset 0 — atomic accumulated)
#define WS_YMEAN     167936    // NEXP*DIM floats
#define WS_XG        200704    // NEXP*CAP*DIM bf16 = 12.6 MB
#define WS_ZERO_BYTES 167936   // counts + zero page + hmean

__device__ __forceinline__ void async_lds16(const void* g, void* l) {
    __builtin_amdgcn_global_load_lds(
        (__attribute__((address_space(1))) void*)(void*)g,
        (__attribute__((address_space(3))) void*)l, 16, 0, 0);
}

// ---------------- K1: gate logits, top-2 softmax, gather x rows (bf16) ------
__global__ __launch_bounds__(256) void k1_route_gather(
    const float* __restrict__ x, const float* __restrict__ gw,
    int* __restrict__ counts, int* __restrict__ top_idx,
    float* __restrict__ routw, __bf16* __restrict__ Xg)
{
    __shared__ float xt[16 * DIM];    // 32 KB: 16 token rows
    __shared__ float lg[16][17];
    __shared__ int   gdst[16][2];
    const int tid = threadIdx.x;
    const int t0  = blockIdx.x * 16;

    {   // stage 16 token rows, coalesced float4
        const float4* src = (const float4*)(x + (size_t)t0 * DIM);
        float4* dst = (float4*)xt;
        #pragma unroll
        for (int i = 0; i < 8; ++i) dst[i * 256 + tid] = src[i * 256 + tid];
    }
    __syncthreads();

    {   // logits: thread = (token tl, expert e)
        const int tl = tid >> 4, e = tid & 15;
        const float4* xr = (const float4*)(xt + tl * DIM);
        const float4* gr = (const float4*)(gw + e * DIM);
        float acc = 0.f;
        #pragma unroll 8
        for (int j = 0; j < DIM / 4; ++j) {
            float4 a = xr[j], b = gr[j];
            acc += a.x * b.x + a.y * b.y + a.z * b.z + a.w * b.w;
        }
        lg[tl][e] = acc;
    }
    __syncthreads();

    if (tid < 16) {   // per-token top-2 + softmax + slot allocation
        const int tl = tid;
        float v0 = -1e30f, v1 = -1e30f; int i0 = 0, i1 = 0;
        #pragma unroll
        for (int e = 0; e < NEXP; ++e) {
            float v = lg[tl][e];
            if (v > v0)      { v1 = v0; i1 = i0; v0 = v; i0 = e; }
            else if (v > v1) { v1 = v;  i1 = e; }
        }
        float e1 = __expf(v1 - v0);          // v0 >= v1
        float w0 = 1.f / (1.f + e1);
        float w1 = 1.f - w0;
        const int t = t0 + tl;
        top_idx[t * 2]     = i0; top_idx[t * 2 + 1] = i1;
        routw[t * 2]       = w0; routw[t * 2 + 1]   = w1;
        int p0 = atomicAdd(counts + i0, 1);
        int p1 = atomicAdd(counts + i1, 1);
        gdst[tl][0] = (p0 < CAP) ? (i0 * CAP + p0) : -1;
        gdst[tl][1] = (p1 < CAP) ? (i1 * CAP + p1) : -1;
    }
    __syncthreads();

    // gather-write 32 rows (16 tokens x 2 experts) as bf16, 8B stores
    #pragma unroll
    for (int it = 0; it < 16; ++it) {
        int s   = it * 256 + tid;          // 0..4095
        int job = s >> 7, el = s & 127;    // job: (token,k), el: float4 index
        int tl  = job >> 1, k = job & 1;
        int dst = gdst[tl][k];
        if (dst >= 0) {
            float4 v = ((const float4*)(xt + tl * DIM))[el];
            bf16x4 o = { (__bf16)v.x, (__bf16)v.y, (__bf16)v.z, (__bf16)v.w };
            *(bf16x4*)(Xg + (size_t)dst * DIM + el * 4) = o;
        }
    }
}

// ---------------- K2: per (expert, 64-f-tile, 128-token-block) --------------
// Round-0 geometry (grid 6x32x16, FT=64, BT=128) with a T3-min 2-phase
// schedule: double-buffered LDS, ONE barrier per K-chunk. Per chunk:
//   issue W1 fp32 loads (next) -> regs   [T14 issue-early]
//   issue X global_load_lds (next, async direct-to-LDS)
//   ds_read frags + 16 MFMA on current buffers
//   cvt + ds_write W1 (next)             [T14 write-late]
//   __syncthreads (drains asyncs + writes)
// grid = NTB(slow) x 32 f-tiles x 16 experts(fast); bid step 512 -> same XCD
// for same (e,f) tile => W1 re-reads across token-blocks are L2 hits.
__global__ __launch_bounds__(256) void k2_expert_ffn(
    const float* __restrict__ w1, const __bf16* __restrict__ Xg,
    const int* __restrict__ counts, const __bf16* __restrict__ zp,
    float* __restrict__ hmean)
{
    __shared__ __align__(16) __bf16 w1s[2][8 * 65 * 8];   // 2 x 8.3 KB [kg][f(+pad)][8]
    __shared__ __align__(16) __bf16 xs[2][8 * 128 * 8];   // 2 x 16 KB  [kg][t][8] linear
    __shared__ float hred[64][2];

    const int tid = threadIdx.x;
    const int bid = blockIdx.x;
    const int tb  = bid >> 9;            // slow: token-block slot
    const int rem = bid & 511;
    const int e   = rem & 15;            // expert fast
    const int f0  = (rem >> 4) * 64;
    const int cnt = min(counts[e], CAP);
    if (tb * BT2 >= cnt) return;         // inactive slot
    const float inv = 1.f / (float)cnt;

    const int wv   = tid >> 6;
    const int lane = tid & 63;
    const int q    = lane >> 4;          // mfma quad
    const int l15  = lane & 15;
    const int fsub = (wv & 1) * 32;
    const int tsub = (wv >> 1) * 64;

    // W1 staging slots (2 per thread): s -> (f = s>>3, g = s&7)
    const int wfA = tid >> 3,        wgA = tid & 7;
    const int wfB = (256 + tid) >> 3, wgB = (256 + tid) & 7;
    const float* w1rowA = w1 + ((size_t)(e * FDIM + f0 + wfA)) * DIM + wgA * 8;
    const float* w1rowB = w1 + ((size_t)(e * FDIM + f0 + wfB)) * DIM + wgB * 8;

    float4 wa0, wb0, wa1, wb1;           // in-flight W1 fp32 (T14 split)

    // ISSUE W1 loads for chunk c (held in regs across the compute phase)
    auto ISSUE_W1 = [&](int c) {
        const float* pA = w1rowA + c * 64;
        const float* pB = w1rowB + c * 64;
        wa0 = ((const float4*)pA)[0]; wb0 = ((const float4*)pA)[1];
        wa1 = ((const float4*)pB)[0]; wb1 = ((const float4*)pB)[1];
    };
    // WRITE W1 (cvt fp32->bf16) into buffer b
    auto WRITE_W1 = [&](int b) {
        bf16x8 v;
        v[0] = (__bf16)wa0.x; v[1] = (__bf16)wa0.y; v[2] = (__bf16)wa0.z; v[3] = (__bf16)wa0.w;
        v[4] = (__bf16)wb0.x; v[5] = (__bf16)wb0.y; v[6] = (__bf16)wb0.z; v[7] = (__bf16)wb0.w;
        *(bf16x8*)(&w1s[b][0] + ((size_t)wgA * 65 + wfA) * 8) = v;
        v[0] = (__bf16)wa1.x; v[1] = (__bf16)wa1.y; v[2] = (__bf16)wa1.z; v[3] = (__bf16)wa1.w;
        v[4] = (__bf16)wb1.x; v[5] = (__bf16)wb1.y; v[6] = (__bf16)wb1.z; v[7] = (__bf16)wb1.w;
        *(bf16x8*)(&w1s[b][0] + ((size_t)wgB * 65 + wfB) * 8) = v;
    };
    // X chunk c -> buffer b, direct global->LDS (wave-uniform dest + lane*16)
    auto STAGE_X = [&](int b, int c) {
        __bf16* dst0 = &xs[b][0];
        #pragma unroll
        for (int it = 0; it < 4; ++it) {
            int base = it * 256 + wv * 64;          // wave-uniform 16B-slot base
            int slot = base + lane;                 // slot = kg*128 + t
            int kg = slot >> 7, t = slot & 127;
            int r  = tb * BT2 + t;
            const __bf16* src = (r < cnt)
                ? (Xg + ((size_t)(e * CAP + r)) * DIM + c * 64 + kg * 8)
                : zp;                               // pad rows read zero page
            async_lds16(src, dst0 + (size_t)base * 8);
        }
    };

    // prologue: fill buffer 0 for chunk 0
    ISSUE_W1(0);
    STAGE_X(0, 0);
    WRITE_W1(0);
    __syncthreads();                     // drains X asyncs + W1 ds_writes

    floatx4 acc[2][4];
    #pragma unroll
    for (int a = 0; a < 2; ++a)
        #pragma unroll
        for (int b = 0; b < 4; ++b) acc[a][b] = (floatx4)0.f;

    int cur = 0;
    for (int c = 0; c < 8; ++c) {        // K chunks of 64
        if (c < 7) {                     // issue next chunk (W1 first, then X)
            ISSUE_W1(c + 1);
            STAGE_X(cur ^ 1, c + 1);
        }
        // compute on current buffers
        const __bf16* wp = &w1s[cur][0];
        const __bf16* xp = &xs[cur][0];
        #pragma unroll
        for (int ks = 0; ks < 2; ++ks) {
            const int kg = ks * 4 + q;
            bf16x8 a0 = *(const bf16x8*)(wp + ((size_t)kg * 65 + fsub + l15) * 8);
            bf16x8 a1 = *(const bf16x8*)(wp + ((size_t)kg * 65 + fsub + 16 + l15) * 8);
            #pragma unroll
            for (int tt = 0; tt < 4; ++tt) {
                bf16x8 bfr = *(const bf16x8*)(xp + ((size_t)kg * 128 + tsub + tt * 16 + l15) * 8);
                acc[0][tt] = __builtin_amdgcn_mfma_f32_16x16x32_bf16(a0, bfr, acc[0][tt], 0, 0, 0);
                acc[1][tt] = __builtin_amdgcn_mfma_f32_16x16x32_bf16(a1, bfr, acc[1][tt], 0, 0, 0);
            }
        }
        if (c < 7) {
            WRITE_W1(cur ^ 1);           // loads landed during compute
            __syncthreads();             // next buffers ready; asyncs drained
            cur ^= 1;
        }
    }

    // silu then column-sum (pad cols give silu(0)=0)
    float hs[8];
    #pragma unroll
    for (int i = 0; i < 8; ++i) hs[i] = 0.f;
    #pragma unroll
    for (int fa = 0; fa < 2; ++fa)
        #pragma unroll
        for (int tt = 0; tt < 4; ++tt)
            #pragma unroll
            for (int r = 0; r < 4; ++r) {
                float v = acc[fa][tt][r];
                hs[fa * 4 + r] += v / (1.f + __expf(-v));
            }

    // sum over the 16 token-columns held across lanes of each quad
    #pragma unroll
    for (int i = 0; i < 8; ++i) {
        float v = hs[i];
        v += __shfl_xor(v, 1);
        v += __shfl_xor(v, 2);
        v += __shfl_xor(v, 4);
        v += __shfl_xor(v, 8);
        hs[i] = v;
    }
    if (l15 == 0) {
        #pragma unroll
        for (int fa = 0; fa < 2; ++fa)
            #pragma unroll
            for (int r = 0; r < 4; ++r) {
                int row = fsub + fa * 16 + q * 4 + r;
                hred[row][wv >> 1] = hs[fa * 4 + r];
            }
    }
    __syncthreads();
    if (tid < 64)
        atomicAdd(hmean + (size_t)e * FDIM + f0 + tid,
                  (hred[tid][0] + hred[tid][1]) * inv);
}

// ---------------- K3: y_mean[e,d] = h_mean[e,:] . w2[e,d,:]  (fp32) ---------
__global__ __launch_bounds__(256) void k3_ymean(
    const float* __restrict__ w2, const float* __restrict__ hmean,
    const int* __restrict__ counts, float* __restrict__ ymean)
{
    __shared__ float hl[FDIM];           // 8 KB
    const int tid = threadIdx.x;
    const int bid = blockIdx.x;
    const int e   = bid >> 7;
    const int d0  = (bid & 127) * 4;

    {
        const float4* hg = (const float4*)(hmean + (size_t)e * FDIM);
        float4* hl4 = (float4*)hl;
        hl4[tid]       = hg[tid];
        hl4[256 + tid] = hg[256 + tid];
    }
    __syncthreads();

    const int wv = tid >> 6, lane = tid & 63;
    const int d = d0 + wv;
    const float4* wr  = (const float4*)(w2 + ((size_t)e * DIM + d) * FDIM);
    const float4* hl4 = (const float4*)hl;
    float acc = 0.f;
    #pragma unroll
    for (int i = 0; i < 8; ++i) {
        float4 a = wr[i * 64 + lane];
        float4 h = hl4[i * 64 + lane];
        acc += a.x * h.x + a.y * h.y + a.z * h.z + a.w * h.w;
    }
    #pragma unroll
    for (int m = 1; m < 64; m <<= 1) acc += __shfl_xor(acc, m);
    if (lane == 0)
        ymean[e * DIM + d] = (counts[e] > 0) ? acc : 0.f;
}

// ---------------- K4: out[t,:] = w0*y[e0,:] + w1*y[e1,:] --------------------
__global__ __launch_bounds__(256) void k4_combine(
    const int* __restrict__ top_idx, const float* __restrict__ routw,
    const float* __restrict__ ymean, float* __restrict__ out)
{
    const int idx = blockIdx.x * 256 + threadIdx.x;   // float4 index
    const int t = idx >> 7;
    const int c = idx & 127;
    const int i0 = top_idx[t * 2], i1 = top_idx[t * 2 + 1];
    const float w0 = routw[t * 2], w1 = routw[t * 2 + 1];
    float4 a = ((const float4*)(ymean + (size_t)i0 * DIM))[c];
    float4 b = ((const float4*)(ymean + (size_t)i1 * DIM))[c];
    float4 o;
    o.x = w0 * a.x + w1 * b.x;
    o.y = w0 * a.y + w1 * b.y;
    o.z = w0 * a.z + w1 * b.z;
    o.w = w0 * a.w + w1 * b.w;
    ((float4*)out)[idx] = o;
}

extern "C" void kernel_launch(void* const* d_in, const int* in_sizes, int n_in,
                              void* d_out, int out_size, void* d_ws, size_t ws_size,
                              hipStream_t stream)
{
    (void)in_sizes; (void)n_in; (void)out_size; (void)ws_size;
    const float* x  = (const float*)d_in[0];   // [4,512,512]
    const float* gw = (const float*)d_in[1];   // [16,512]
    const float* w1 = (const float*)d_in[2];   // [16,2048,512]
    const float* w2 = (const float*)d_in[3];   // [16,512,2048]
    float* out = (float*)d_out;

    char* ws = (char*)d_ws;
    int*    counts  = (int*)   (ws + WS_COUNTS);
    const __bf16* zp = (const __bf16*)(ws + WS_ZEROPAGE);
    int*    top_idx = (int*)   (ws + WS_TOPIDX);
    float*  routw   = (float*) (ws + WS_ROUTW);
    float*  hmean   = (float*) (ws + WS_HMEAN);
    float*  ymean   = (float*) (ws + WS_YMEAN);
    __bf16* Xg      = (__bf16*)(ws + WS_XG);

    hipMemsetAsync(d_ws, 0, WS_ZERO_BYTES, stream);   // counts + zero page + hmean

    k1_route_gather<<<dim3(NTOK / 16), dim3(256), 0, stream>>>(x, gw, counts, top_idx, routw, Xg);
    k2_expert_ffn  <<<dim3(NTB * 32 * NEXP), dim3(256), 0, stream>>>(w1, Xg, counts, zp, hmean);
    k3_ymean       <<<dim3(NEXP * 128), dim3(256), 0, stream>>>(w2, hmean, counts, ymean);
    k4_combine     <<<dim3(NTOK * DIM / 4 / 256), dim3(256), 0, stream>>>(top_idx, routw, ymean, out);
}